// Round 1
// baseline (7228.857 us; speedup 1.0000x reference)
//
#include <hip/hip_runtime.h>
#include <hip/hip_cooperative_groups.h>

namespace cg = cooperative_groups;

#define NWG 256
#define NT  256
#define B_  64
#define T_  128
#define U_  1024
#define C3  3072
// LDS: U/W tile [24][1024] f32 + rec scratch [2][64][12] f32
#define SMEM_BYTES ((24*1024 + 2*64*12) * 4)

__device__ __forceinline__ float sigm(float x){ return 1.f/(1.f+__expf(-x)); }
// NaN-safe tanh: x->+inf => 1, x->-inf => -1
__device__ __forceinline__ float tanh_(float x){ return 1.f - 2.f/(1.f+__expf(2.f*x)); }

__global__ void __launch_bounds__(NT, 1)
enc_kernel(const int* __restrict__ tok,
           const float* __restrict__ emb,
           const float* __restrict__ Wf, const float* __restrict__ Uf, const float* __restrict__ bfp,
           const float* __restrict__ Wb, const float* __restrict__ Ub, const float* __restrict__ bbp,
           float* __restrict__ out, float* __restrict__ ws)
{
  extern __shared__ float sm[];
  float* Ul   = sm;             // [24 cols][1024 k]  (W during phase A, then U)
  float* recl = sm + 24*1024;   // [2 d][64 b][12 c]

  const int tid = threadIdx.x, wg = blockIdx.x;
  const int u0 = wg*4;                       // this WG owns units u0..u0+3 per direction

  float* xpv  = ws;                          // [6144 c][128 vocab]  (= emb_table@W + b0, gathered by token)
  float* embT = ws + 6144*128;               // [1024 k][128 v]
  float* hg   = ws + 6144*128 + 1024*128;    // [2 buf][2 d][1024 u][64 b]

  cg::grid_group grid = cg::this_grid();
  const int gtid = wg*NT + tid;

  // ---- prologue: zero h buffer 0; transpose emb_table -> embT ----
  for (int i = gtid; i < 2*1024*64; i += NWG*NT) hg[i] = 0.f;
  for (int i = gtid; i < 128*1024; i += NWG*NT)
    embT[(i & 1023)*128 + (i >> 10)] = emb[i];

  // ---- load W columns for our 24 cols into LDS (phase A uses dot6 with W) ----
  #pragma unroll
  for (int i = 0; i < 24; ++i) {
    int flat = tid + i*NT;                   // 0..6143  -> (k, d, g)
    int k = flat / 6, rem = flat % 6;
    int dd = rem / 3, g = rem % 3;
    const float* M = dd ? Wb : Wf;
    float4 v4 = *(const float4*)&M[k*C3 + g*U_ + u0];   // units u0..u0+3, gate g
    // lc = d*12 + uu*6 + ul*3 + g  with unit offset ulf = uu*2+ul
    Ul[(dd*12 + 0 + g)*1024 + k] = v4.x;
    Ul[(dd*12 + 3 + g)*1024 + k] = v4.y;
    Ul[(dd*12 + 6 + g)*1024 + k] = v4.z;
    Ul[(dd*12 + 9 + g)*1024 + k] = v4.w;
  }
  grid.sync();   // embT + h-zero visible; also block barrier for Ul

  // ---- wave identity: wave wv = (d, uu); lanes = (bq 0..15, kq 0..3) ----
  const int lane = tid & 63, wv = tid >> 6;
  const int d = wv >> 1, uu = wv & 1;
  const int bq = lane & 15, kq = lane >> 4;
  const float* ulds = Ul + (d*12 + uu*6)*1024;

  // dot over k=1024 for 6 columns x 4 rows/lane; k split 4-way over kq lanes,
  // butterfly-reduced; lane (bq,kq) returns row b = bq*4+kq.
  auto dot6 = [&](const float* src, int rs, float* r) {
    float acc[6][4];
    #pragma unroll
    for (int j=0;j<6;++j){acc[j][0]=acc[j][1]=acc[j][2]=acc[j][3]=0.f;}
    for (int kit = 0; kit < 64; ++kit) {
      float4 uv[6];
      #pragma unroll
      for (int j=0;j<6;++j) uv[j] = *(const float4*)(ulds + j*1024 + kq*256 + kit*4);
      #pragma unroll
      for (int kk=0;kk<4;++kk) {
        float4 h4 = *(const float4*)(src + (kit*4+kk)*rs);
        #pragma unroll
        for (int j=0;j<6;++j) {
          float w = kk==0?uv[j].x : kk==1?uv[j].y : kk==2?uv[j].z : uv[j].w;
          acc[j][0] += h4.x*w; acc[j][1] += h4.y*w;
          acc[j][2] += h4.z*w; acc[j][3] += h4.w*w;
        }
      }
    }
    #pragma unroll
    for (int j=0;j<6;++j){
      #pragma unroll
      for (int bi=0;bi<4;++bi){
        float v = acc[j][bi];
        v += __shfl_xor(v, 16, 64);
        v += __shfl_xor(v, 32, 64);
        acc[j][bi] = v;
      }
      r[j] = kq==0?acc[j][0] : kq==1?acc[j][1] : kq==2?acc[j][2] : acc[j][3];
    }
  };

  // ---- phase A: xpv[c][v] = emb_table @ W + b[0], for our 24 cols ----
  {
    const float* bias_d = d ? bbp : bfp;
    for (int half = 0; half < 2; ++half) {
      float r[6];
      dot6(embT + (kq*256)*128 + half*64 + bq*4, 128, r);
      int v = half*64 + bq*4 + kq;
      #pragma unroll
      for (int j=0;j<6;++j){
        int ul = j/3, g = j%3;
        int cp = g*U_ + u0 + uu*2 + ul;
        xpv[(d*C3 + cp)*128 + v] = r[j] + bias_d[cp];
      }
    }
  }
  __syncthreads();
  // ---- swap LDS contents: now load recurrent U ----
  #pragma unroll
  for (int i = 0; i < 24; ++i) {
    int flat = tid + i*NT;
    int k = flat / 6, rem = flat % 6;
    int dd = rem / 3, g = rem % 3;
    const float* M = dd ? Ub : Uf;
    float4 v4 = *(const float4*)&M[k*C3 + g*U_ + u0];
    Ul[(dd*12 + 0 + g)*1024 + k] = v4.x;
    Ul[(dd*12 + 3 + g)*1024 + k] = v4.y;
    Ul[(dd*12 + 6 + g)*1024 + k] = v4.z;
    Ul[(dd*12 + 9 + g)*1024 + k] = v4.w;
  }
  __syncthreads();

  // ---- recurrence: 128 lockstep steps (fwd t=s, bwd t=127-s), 1 grid.sync each ----
  for (int s = 0; s < T_; ++s) {
    const float* hc = hg + (s&1)*(2*1024*64);
    float*       hn = hg + ((s+1)&1)*(2*1024*64);

    float r[6];
    dot6(hc + (d*1024 + kq*256)*64 + bq*4, 64, r);
    const int b = bq*4 + kq;
    #pragma unroll
    for (int j=0;j<6;++j) recl[(d*64 + b)*12 + uu*6 + j] = r[j];
    __syncthreads();

    {  // gate phase: remap threads to (gd, guu, gb)
      const int gd = tid >> 7, guu = (tid >> 6) & 1, gb = tid & 63;
      const int t = gd ? (T_-1 - s) : s;
      const int tk = tok[gb*T_ + t];
      const bool msk = (tk != 0);
      const float* bias = gd ? bbp : bfp;
      float o[2];
      #pragma unroll
      for (int ul=0; ul<2; ++ul) {
        const int u = u0 + guu*2 + ul;
        const int rb = (gd*64+gb)*12 + guu*6 + ul*3;
        float rz = recl[rb+0] + bias[C3 + u];
        float rr = recl[rb+1] + bias[C3 + U_ + u];
        float rh = recl[rb+2] + bias[C3 + 2*U_ + u];
        float xz = xpv[(gd*C3 +          u)*128 + tk];
        float xr = xpv[(gd*C3 +   U_  +  u)*128 + tk];
        float xh = xpv[(gd*C3 + 2*U_  +  u)*128 + tk];
        float hold = hc[(gd*1024 + u)*64 + gb];
        float z  = sigm(xz + rz);
        float rg = sigm(xr + rr);
        float th = tanh_(xh + rg*rh);
        float hnew = z*hold + (1.f - z)*th;
        float hx = msk ? hnew : hold;          // out_t == h_t (mask freezes both)
        hn[(gd*1024 + u)*64 + gb] = hx;
        o[ul] = hx;
      }
      // fwd writes t=s, bwd writes t=127-s; the step<64 writer is always first
      float2* op = (float2*)(out + (gb*T_ + t)*U_ + u0 + guu*2);
      if (s < 64) { *op = make_float2(o[0], o[1]); }
      else        { float2 pv = *op; *op = make_float2(pv.x + o[0], pv.y + o[1]); }
    }
    grid.sync();
  }
}

extern "C" void kernel_launch(void* const* d_in, const int* in_sizes, int n_in,
                              void* d_out, int out_size, void* d_ws, size_t ws_size,
                              hipStream_t stream) {
  const int*   tok = (const int*)  d_in[0];
  const float* emb = (const float*)d_in[1];
  const float* Wf  = (const float*)d_in[2];
  const float* Uf  = (const float*)d_in[3];
  const float* bfp = (const float*)d_in[4];
  const float* Wb  = (const float*)d_in[5];
  const float* Ub  = (const float*)d_in[6];
  const float* bbp = (const float*)d_in[7];
  float* outp = (float*)d_out;
  float* wsp  = (float*)d_ws;

  static bool attr_done = false;
  (void)attr_done;
  hipFuncSetAttribute((const void*)enc_kernel,
                      hipFuncAttributeMaxDynamicSharedMemorySize, SMEM_BYTES);

  void* args[] = { (void*)&tok, (void*)&emb, (void*)&Wf, (void*)&Uf, (void*)&bfp,
                   (void*)&Wb, (void*)&Ub, (void*)&bbp, (void*)&outp, (void*)&wsp };
  hipLaunchCooperativeKernel((const void*)enc_kernel, dim3(NWG), dim3(NT),
                             args, SMEM_BYTES, stream);
}

// Round 3
// 5922.313 us; speedup vs baseline: 1.2206x; 1.2206x over previous
//
#include <hip/hip_runtime.h>
#include <hip/hip_cooperative_groups.h>

namespace cg = cooperative_groups;

#define NWG 256
#define NT  512
#define B_  64
#define T_  128
#define U_  1024
#define C3  3072

// Padded U/W column: 16 chunks of (64+4) floats -> kq slices land on distinct banks
#define COLSTRIDE 1088
#define U_LDS_FLOATS (24*COLSTRIDE)          // 104448 B
#define P_OFF   U_LDS_FLOATS                 // P: [24 dc][4 kh][64 b] = 6144 floats
#define REC_OFF (P_OFF + 6144)               // rec: 1536 floats
#define SMEM_BYTES ((U_LDS_FLOATS + 6144 + 1536)*4)   // 135168 B -> 1 WG/CU, 8 waves

__device__ __forceinline__ float sigm(float x){ return 1.f/(1.f+__expf(-x)); }
__device__ __forceinline__ float tanh_(float x){ return 1.f - 2.f/(1.f+__expf(2.f*x)); }

__global__ void __launch_bounds__(NT, 2)
enc_kernel(const int* __restrict__ tok,
           const float* __restrict__ emb,
           const float* __restrict__ Wf, const float* __restrict__ Uf, const float* __restrict__ bfp,
           const float* __restrict__ Wb, const float* __restrict__ Ub, const float* __restrict__ bbp,
           float* __restrict__ out, float* __restrict__ ws)
{
  extern __shared__ float sm[];
  float* Ul   = sm;
  float* Pl   = sm + P_OFF;
  float* recl = sm + REC_OFF;

  const int tid = threadIdx.x, wg = blockIdx.x;
  const int u0 = wg*4;                       // 4 units per direction per WG

  float* xpv  = ws;                          // [2*3072 c][128 v] = emb@W + b0 (token-gatherable)
  float* embT = ws + 6144*128;               // [1024 k][128 v]
  float* hg   = ws + 6144*128 + 1024*128;    // [2 buf][2 d][1024 u][64 b]

  cg::grid_group grid = cg::this_grid();
  const int gtid = wg*NT + tid;

  // ---- prologue: zero h buf0; transpose emb -> embT (each exactly 1 elem/thread) ----
  for (int i = gtid; i < 2*1024*64; i += NWG*NT) hg[i] = 0.f;
  for (int i = gtid; i < 128*1024; i += NWG*NT)
    embT[(i & 1023)*128 + (i >> 10)] = emb[i];

  // ---- loader: 24 cols (2d x 4units x 3gates) x 1024 k into padded LDS ----
  auto loadMat = [&](const float* Mf_, const float* Mb_) {
    #pragma unroll
    for (int i = 0; i < 12; ++i) {
      int flat = tid + i*NT;                 // 0..6143 -> (k, d, g)
      int k = flat / 6, rem = flat % 6;
      int dd = rem / 3, g = rem % 3;
      const float* M = dd ? Mb_ : Mf_;
      float4 v4 = *(const float4*)&M[k*C3 + g*U_ + u0];
      int koff = (k >> 6)*68 + (k & 63);
      Ul[(dd*12 + 0*3 + g)*COLSTRIDE + koff] = v4.x;
      Ul[(dd*12 + 1*3 + g)*COLSTRIDE + koff] = v4.y;
      Ul[(dd*12 + 2*3 + g)*COLSTRIDE + koff] = v4.z;
      Ul[(dd*12 + 3*3 + g)*COLSTRIDE + koff] = v4.w;
    }
  };

  loadMat(Wf, Wb);                           // phase A uses W
  grid.sync();                               // embT + h-zero grid-visible; W block-visible

  // ---- wave identity: 8 waves = (d, kh quarter); lanes = (bq 0..15, kq 0..3) ----
  const int lane = tid & 63, wv = tid >> 6;
  const int d = wv >> 2, kh = wv & 3;
  const int bq = lane & 15, kq = lane >> 4;
  const float* ubase = Ul + (d*12)*COLSTRIDE + (kh*4 + kq)*68;

  // 12 cols x 4 rows/lane over this wave's 256-k quarter (kq sub-splits by 64 k).
  // After butterfly over kq bits, lane (bq,kq) holds row b=bq*4+kq summed over the quarter.
  auto dot12 = [&](const float* src, int rs, float* r) {
    float acc[12][4];
    #pragma unroll
    for (int j=0;j<12;++j){acc[j][0]=acc[j][1]=acc[j][2]=acc[j][3]=0.f;}
    for (int kit = 0; kit < 16; ++kit) {
      float4 uv[12];
      #pragma unroll
      for (int j=0;j<12;++j) uv[j] = *(const float4*)(ubase + j*COLSTRIDE + kit*4);
      #pragma unroll
      for (int kk=0;kk<4;++kk) {
        float4 h4 = *(const float4*)(src + (kit*4+kk)*rs);
        #pragma unroll
        for (int j=0;j<12;++j) {
          float w = kk==0?uv[j].x : kk==1?uv[j].y : kk==2?uv[j].z : uv[j].w;
          acc[j][0] += h4.x*w; acc[j][1] += h4.y*w;
          acc[j][2] += h4.z*w; acc[j][3] += h4.w*w;
        }
      }
    }
    #pragma unroll
    for (int j=0;j<12;++j){
      #pragma unroll
      for (int bi=0;bi<4;++bi){
        float v = acc[j][bi];
        v += __shfl_xor(v, 16, 64);
        v += __shfl_xor(v, 32, 64);
        acc[j][bi] = v;
      }
      r[j] = kq==0?acc[j][0] : kq==1?acc[j][1] : kq==2?acc[j][2] : acc[j][3];
    }
  };

  // ---- phase A: xpv[c][v] = emb@W + b0 for our 24 cols (two 64-vocab halves) ----
  for (int half = 0; half < 2; ++half) {
    float r[12];
    dot12(embT + (kh*256 + kq*64)*128 + half*64 + bq*4, 128, r);
    const int vv = bq*4 + kq;
    #pragma unroll
    for (int j=0;j<12;++j) Pl[(d*12+j)*256 + kh*64 + vv] = r[j];
    __syncthreads();
    for (int e = tid; e < 1536; e += NT) {
      int dc = e >> 6, v = e & 63;
      float s_ = Pl[dc*256 + v] + Pl[dc*256 + 64 + v] + Pl[dc*256 + 128 + v] + Pl[dc*256 + 192 + v];
      int dd = dc / 12, c = dc % 12;
      int ul = c / 3, g = c % 3;
      int cp = g*U_ + u0 + ul;
      const float* brow = dd ? bbp : bfp;
      xpv[(dd*C3 + cp)*128 + half*64 + v] = s_ + brow[cp];
    }
    __syncthreads();
  }

  // ---- swap in recurrent U ----
  loadMat(Uf, Ub);
  __syncthreads();

  // hoist gate-phase constants
  const int gd = tid >> 8, grm = tid & 255, gb = grm >> 2, gul = grm & 3;
  const int gu = u0 + gul;
  const float* brow1 = (gd ? bbp : bfp) + C3;
  const float bz1 = brow1[gu], br1 = brow1[U_ + gu], bh1 = brow1[2*U_ + gu];

  // ---- recurrence: 128 lockstep steps ----
  for (int s = 0; s < T_; ++s) {
    const float* hc = hg + (s&1)*(2*1024*64);
    float*       hn = hg + ((s+1)&1)*(2*1024*64);

    float r[12];
    dot12(hc + (d*1024 + kh*256 + kq*64)*64 + bq*4, 64, r);
    const int b = bq*4 + kq;
    #pragma unroll
    for (int j=0;j<12;++j) Pl[(d*12+j)*256 + kh*64 + b] = r[j];
    __syncthreads();

    #pragma unroll
    for (int e = tid, it = 0; it < 3; ++it, e += NT) {
      int dc = e >> 6, v = e & 63;
      recl[e] = Pl[dc*256 + v] + Pl[dc*256 + 64 + v] + Pl[dc*256 + 128 + v] + Pl[dc*256 + 192 + v];
    }
    __syncthreads();

    {  // gate phase: thread = (gd, gb, gul) -> one unit
      const int t = gd ? (T_-1 - s) : s;
      const int tk = tok[gb*T_ + t];
      const bool msk = (tk != 0);
      const int rb = (gd*12 + gul*3)*64 + gb;
      float rz = recl[rb]        + bz1;
      float rr = recl[rb + 64]   + br1;
      float rh = recl[rb + 128]  + bh1;
      float xz = xpv[(gd*C3 +          gu)*128 + tk];
      float xr = xpv[(gd*C3 +   U_  +  gu)*128 + tk];
      float xh = xpv[(gd*C3 + 2*U_  +  gu)*128 + tk];
      float hold = hc[(gd*1024 + gu)*64 + gb];
      float z  = sigm(xz + rz);
      float rg = sigm(xr + rr);
      float th = tanh_(xh + rg*rh);
      float hnew = z*hold + (1.f - z)*th;
      float hx = msk ? hnew : hold;          // out_t == h_t (mask freezes both)
      hn[(gd*1024 + gu)*64 + gb] = hx;
      float* op = out + (gb*T_ + t)*U_ + gu;
      if (s < 64) *op = hx; else *op += hx;
    }
    grid.sync();
  }
}

extern "C" void kernel_launch(void* const* d_in, const int* in_sizes, int n_in,
                              void* d_out, int out_size, void* d_ws, size_t ws_size,
                              hipStream_t stream) {
  const int*   tok = (const int*)  d_in[0];
  const float* emb = (const float*)d_in[1];
  const float* Wf  = (const float*)d_in[2];
  const float* Uf  = (const float*)d_in[3];
  const float* bfp = (const float*)d_in[4];
  const float* Wb  = (const float*)d_in[5];
  const float* Ub  = (const float*)d_in[6];
  const float* bbp = (const float*)d_in[7];
  float* outp = (float*)d_out;
  float* wsp  = (float*)d_ws;

  hipFuncSetAttribute((const void*)enc_kernel,
                      hipFuncAttributeMaxDynamicSharedMemorySize, SMEM_BYTES);

  void* args[] = { (void*)&tok, (void*)&emb, (void*)&Wf, (void*)&Uf, (void*)&bfp,
                   (void*)&Wb, (void*)&Ub, (void*)&bbp, (void*)&outp, (void*)&wsp };
  hipLaunchCooperativeKernel((const void*)enc_kernel, dim3(NWG), dim3(NT),
                             args, SMEM_BYTES, stream);
}